// Round 3
// baseline (3440.572 us; speedup 1.0000x reference)
//
#include <hip/hip_runtime.h>

// Op: out = (1/num_op) * sum_i ws[i] * SpMM(A_i, x).
// Pipeline: bucket-count -> small scan -> bucket-scatter (coarse sort by row>>6)
//           -> per-bucket LDS-accumulate consume.
// N=50000, D=128, NUM_OP=8, E=400000.

#define D_DIM 128
#define RPB_SHIFT 6
#define RPB 64                  // rows per bucket
#define MAX_BUCKETS 1024        // LDS histogram capacity (B = 782)

// ---------- fallback (round-0) atomic scatter kernel ----------
__global__ __launch_bounds__(256) void spmm_scatter_kernel(
    const float* __restrict__ x, const float* __restrict__ edge_vals,
    const float* __restrict__ ws, const int* __restrict__ edge_rows,
    const int* __restrict__ edge_cols, float* __restrict__ out,
    int E, float inv_num)
{
    const int  op   = blockIdx.y;
    const long base = (long)op * (long)E;
    const float wscale = ws[op] * inv_num;
    const int lane = threadIdx.x & 63;
    const int wave = blockIdx.x * (blockDim.x >> 6) + (threadIdx.x >> 6);
    const int nwaves = gridDim.x * (blockDim.x >> 6);
    for (int e = wave; e < E; e += nwaves) {
        const int row = edge_rows[base + e];
        const int col = edge_cols[base + e];
        const float v = edge_vals[base + e] * wscale;
        const float2 xv = *reinterpret_cast<const float2*>(x + (long)col * D_DIM + lane * 2);
        float* o = out + (long)row * D_DIM + lane * 2;
        atomicAdd(o, xv.x * v);
        atomicAdd(o + 1, xv.y * v);
    }
}

// ---------- 1. bucket count (LDS-aggregated histogram) ----------
__global__ __launch_bounds__(256) void bucket_count_kernel(
    const int* __restrict__ edge_rows, int* __restrict__ counts, int E, int B)
{
    __shared__ int h[MAX_BUCKETS];
    for (int i = threadIdx.x; i < B; i += blockDim.x) h[i] = 0;
    __syncthreads();
    const long base = (long)blockIdx.y * (long)E;
    for (int e = blockIdx.x * blockDim.x + threadIdx.x; e < E;
         e += gridDim.x * blockDim.x)
        atomicAdd(&h[edge_rows[base + e] >> RPB_SHIFT], 1);
    __syncthreads();
    for (int i = threadIdx.x; i < B; i += blockDim.x)
        if (h[i]) atomicAdd(&counts[i], h[i]);
}

// ---------- 2. exclusive scan of B<=1024 counts (single block) ----------
__global__ __launch_bounds__(1024) void scan_small_kernel(
    int* __restrict__ cursors, int* __restrict__ offsets, int B)
{
    __shared__ int s[1024];
    const int tid = threadIdx.x;
    const int v = (tid < B) ? cursors[tid] : 0;
    s[tid] = v;
    __syncthreads();
    for (int ofs = 1; ofs < 1024; ofs <<= 1) {
        const int t = (tid >= ofs) ? s[tid - ofs] : 0;
        __syncthreads();
        s[tid] += t;
        __syncthreads();
    }
    if (tid < B) {
        const int excl = s[tid] - v;     // exclusive prefix
        offsets[tid] = excl;
        cursors[tid] = excl;
        if (tid == B - 1) offsets[B] = s[tid];
    }
}

// ---------- 3. scatter records into buckets ----------
__global__ __launch_bounds__(256) void bucket_scatter_kernel(
    const int* __restrict__ edge_rows, const int* __restrict__ edge_cols,
    const float* __restrict__ edge_vals, const float* __restrict__ ws,
    int* __restrict__ cursors, int2* __restrict__ records,
    int E, float inv_num)
{
    const int  op   = blockIdx.y;
    const long base = (long)op * (long)E;
    const float wscale = ws[op] * inv_num;
    for (int e = blockIdx.x * blockDim.x + threadIdx.x; e < E;
         e += gridDim.x * blockDim.x) {
        const int row = edge_rows[base + e];
        const int col = edge_cols[base + e];
        const float v = edge_vals[base + e] * wscale;
        const int pos = atomicAdd(&cursors[row >> RPB_SHIFT], 1);
        // pack: row-within-bucket (6b) << 16 | col (16b, N=50000<65536)
        records[pos] = make_int2(((row & (RPB - 1)) << 16) | col, __float_as_int(v));
    }
}

// ---------- 4. consume: one block per bucket, LDS accumulator ----------
__global__ __launch_bounds__(256) void consume_kernel(
    const float* __restrict__ x, const int* __restrict__ boff,
    const int2* __restrict__ records, float* __restrict__ out, int N)
{
    __shared__ float acc[RPB * D_DIM];          // 32 KB
    const int b     = blockIdx.x;
    const int row0  = b << RPB_SHIFT;
    const int nrows = min(RPB, N - row0);

    for (int i = threadIdx.x; i < RPB * D_DIM / 4; i += blockDim.x)
        reinterpret_cast<float4*>(acc)[i] = make_float4(0.f, 0.f, 0.f, 0.f);
    __syncthreads();

    const int lane = threadIdx.x & 63;
    const int wv   = threadIdx.x >> 6;          // 0..3
    const int start = boff[b], end = boff[b + 1];

    int e = start + wv * 2;
    for (; e + 1 < end; e += 8) {               // 2-unrolled, 4 waves x 2
        const int2 r0 = records[e];
        const int2 r1 = records[e + 1];
        const int  rl0 = r0.x >> 16, c0 = r0.x & 0xFFFF;
        const int  rl1 = r1.x >> 16, c1 = r1.x & 0xFFFF;
        const float v0 = __int_as_float(r0.y);
        const float v1 = __int_as_float(r1.y);
        const float xa0 = x[c0 * D_DIM + lane];
        const float xb0 = x[c0 * D_DIM + 64 + lane];
        const float xa1 = x[c1 * D_DIM + lane];
        const float xb1 = x[c1 * D_DIM + 64 + lane];
        atomicAdd(&acc[rl0 * D_DIM + lane],      v0 * xa0);
        atomicAdd(&acc[rl0 * D_DIM + 64 + lane], v0 * xb0);
        atomicAdd(&acc[rl1 * D_DIM + lane],      v1 * xa1);
        atomicAdd(&acc[rl1 * D_DIM + 64 + lane], v1 * xb1);
    }
    if (e < end) {
        const int2 r0 = records[e];
        const int  rl0 = r0.x >> 16, c0 = r0.x & 0xFFFF;
        const float v0 = __int_as_float(r0.y);
        const float xa0 = x[c0 * D_DIM + lane];
        const float xb0 = x[c0 * D_DIM + 64 + lane];
        atomicAdd(&acc[rl0 * D_DIM + lane],      v0 * xa0);
        atomicAdd(&acc[rl0 * D_DIM + 64 + lane], v0 * xb0);
    }
    __syncthreads();

    // coalesced block write: rows row0..row0+nrows are contiguous in out
    const int nflt4 = nrows * (D_DIM / 4);
    float4* out4 = reinterpret_cast<float4*>(out + (long)row0 * D_DIM);
    const float4* a4 = reinterpret_cast<const float4*>(acc);
    for (int i = threadIdx.x; i < nflt4; i += blockDim.x) out4[i] = a4[i];
}

extern "C" void kernel_launch(void* const* d_in, const int* in_sizes, int n_in,
                              void* d_out, int out_size, void* d_ws, size_t ws_size,
                              hipStream_t stream)
{
    const float* x         = (const float*)d_in[0];
    const float* edge_vals = (const float*)d_in[1];
    const float* ws        = (const float*)d_in[2];
    const int*   edge_rows = (const int*)d_in[3];
    const int*   edge_cols = (const int*)d_in[4];
    float*       out       = (float*)d_out;

    const int num_op = in_sizes[2];               // 8
    const int E      = in_sizes[1] / num_op;      // 400000
    const int N      = in_sizes[0] / D_DIM;       // 50000
    const long Etot  = (long)num_op * (long)E;    // 3.2M
    const int  B     = (N + RPB - 1) / RPB;       // 782 buckets
    const float inv_num = 1.0f / (float)num_op;

    // workspace layout
    const size_t off_offsets = 0;
    const size_t off_cursors = ((size_t)(B + 1) * 4 + 255) & ~(size_t)255;
    const size_t off_records = (off_cursors + (size_t)B * 4 + 255) & ~(size_t)255;
    const size_t need        = off_records + (size_t)Etot * 8;

    if (ws_size < need || B > MAX_BUCKETS) {
        hipMemsetAsync(d_out, 0, (size_t)out_size * sizeof(float), stream);
        dim3 grid(256, num_op, 1);
        spmm_scatter_kernel<<<grid, 256, 0, stream>>>(
            x, edge_vals, ws, edge_rows, edge_cols, out, E, inv_num);
        return;
    }

    int*  offsets = (int*)((char*)d_ws + off_offsets);
    int*  cursors = (int*)((char*)d_ws + off_cursors);
    int2* records = (int2*)((char*)d_ws + off_records);

    hipMemsetAsync(cursors, 0, (size_t)B * 4, stream);

    dim3 cgrid(32, num_op, 1);
    bucket_count_kernel<<<cgrid, 256, 0, stream>>>(edge_rows, cursors, E, B);
    scan_small_kernel<<<1, 1024, 0, stream>>>(cursors, offsets, B);
    dim3 sgrid(128, num_op, 1);
    bucket_scatter_kernel<<<sgrid, 256, 0, stream>>>(
        edge_rows, edge_cols, edge_vals, ws, cursors, records, E, inv_num);
    consume_kernel<<<B, 256, 0, stream>>>(x, offsets, records, out, N);
}

// Round 4
// 670.953 us; speedup vs baseline: 5.1279x; 5.1279x over previous
//
#include <hip/hip_runtime.h>

// Op: out = (1/num_op) * sum_i ws[i] * SpMM(A_i, x).
// Pipeline: x->bf16 convert | row histogram | 50K exclusive scan |
//           COO->CSR scatter (nt stores) | wave-per-row gather (shfl-broadcast records).
// N=50000, D=128, NUM_OP=8, E=400000.

#define D_DIM 128
#define SCAN_BLOCK 1024

static __device__ __forceinline__ unsigned short f2bf(float f) {
    unsigned int u = __float_as_uint(f);
    u += 0x7FFFu + ((u >> 16) & 1u);          // round-to-nearest-even
    return (unsigned short)(u >> 16);
}

// ---------- fallback (round-0) atomic scatter kernel ----------
__global__ __launch_bounds__(256) void spmm_scatter_kernel(
    const float* __restrict__ x, const float* __restrict__ edge_vals,
    const float* __restrict__ ws, const int* __restrict__ edge_rows,
    const int* __restrict__ edge_cols, float* __restrict__ out,
    int E, float inv_num)
{
    const int  op   = blockIdx.y;
    const long base = (long)op * (long)E;
    const float wscale = ws[op] * inv_num;
    const int lane = threadIdx.x & 63;
    const int wave = blockIdx.x * (blockDim.x >> 6) + (threadIdx.x >> 6);
    const int nwaves = gridDim.x * (blockDim.x >> 6);
    for (int e = wave; e < E; e += nwaves) {
        const int row = edge_rows[base + e];
        const int col = edge_cols[base + e];
        const float v = edge_vals[base + e] * wscale;
        const float2 xv = *reinterpret_cast<const float2*>(x + (long)col * D_DIM + lane * 2);
        float* o = out + (long)row * D_DIM + lane * 2;
        atomicAdd(o, xv.x * v);
        atomicAdd(o + 1, xv.y * v);
    }
}

// ---------- 0. x (f32) -> bf16 ----------
__global__ __launch_bounds__(256) void convert_kernel(
    const float4* __restrict__ x4, unsigned long long* __restrict__ xh, int n4)
{
    const int stride = gridDim.x * blockDim.x;
    for (int i = blockIdx.x * blockDim.x + threadIdx.x; i < n4; i += stride) {
        const float4 v = x4[i];
        const unsigned long long p =
            (unsigned long long)f2bf(v.x)
            | ((unsigned long long)f2bf(v.y) << 16)
            | ((unsigned long long)f2bf(v.z) << 32)
            | ((unsigned long long)f2bf(v.w) << 48);
        xh[i] = p;
    }
}

// ---------- 1. row histogram ----------
__global__ __launch_bounds__(256) void histogram_kernel(
    const int* __restrict__ edge_rows, int* __restrict__ counts, int E)
{
    const long base = (long)blockIdx.y * (long)E;
    for (int e = blockIdx.x * blockDim.x + threadIdx.x; e < E;
         e += gridDim.x * blockDim.x)
        atomicAdd(&counts[__builtin_nontemporal_load(&edge_rows[base + e])], 1);
}

// ---------- 2. exclusive scan of counts[N] (single block, proven) ----------
__global__ __launch_bounds__(SCAN_BLOCK) void scan_kernel(
    int* __restrict__ cursors, int* __restrict__ offsets, int N)
{
    __shared__ int sdata[SCAN_BLOCK];
    __shared__ int carry_s;
    if (threadIdx.x == 0) carry_s = 0;
    __syncthreads();
    for (int base = 0; base < N; base += SCAN_BLOCK) {
        const int i = base + (int)threadIdx.x;
        const int v = (i < N) ? cursors[i] : 0;
        sdata[threadIdx.x] = v;
        __syncthreads();
        for (int ofs = 1; ofs < SCAN_BLOCK; ofs <<= 1) {
            int t = (threadIdx.x >= (unsigned)ofs) ? sdata[threadIdx.x - ofs] : 0;
            __syncthreads();
            sdata[threadIdx.x] += t;
            __syncthreads();
        }
        const int incl  = sdata[threadIdx.x];
        const int carry = carry_s;
        if (i < N) {
            const int excl = carry + incl - v;
            offsets[i] = excl;
            cursors[i] = excl;
        }
        __syncthreads();
        if (threadIdx.x == SCAN_BLOCK - 1) carry_s = carry + incl;
        __syncthreads();
    }
    if (threadIdx.x == 0) offsets[N] = carry_s;
}

// ---------- 3. COO -> CSR scatter, nt streaming stores ----------
__global__ __launch_bounds__(256) void scatter_build_kernel(
    const int* __restrict__ edge_rows, const int* __restrict__ edge_cols,
    const float* __restrict__ edge_vals, const float* __restrict__ ws,
    int* __restrict__ cursors, unsigned long long* __restrict__ records,
    int E, float inv_num)
{
    const int  op   = blockIdx.y;
    const long base = (long)op * (long)E;
    const float wscale = ws[op] * inv_num;
    for (int e = blockIdx.x * blockDim.x + threadIdx.x; e < E;
         e += gridDim.x * blockDim.x) {
        const int   row = __builtin_nontemporal_load(&edge_rows[base + e]);
        const int   col = __builtin_nontemporal_load(&edge_cols[base + e]);
        const float v   = __builtin_nontemporal_load(&edge_vals[base + e]) * wscale;
        const int pos = atomicAdd(&cursors[row], 1);
        const unsigned long long rec =
            ((unsigned long long)__float_as_uint(v) << 32) | (unsigned int)col;
        __builtin_nontemporal_store(rec, &records[pos]);
    }
}

// ---------- 4a. gather, bf16 x: wave per row, shfl-broadcast records ----------
__global__ __launch_bounds__(256) void gather_bf16_kernel(
    const unsigned short* __restrict__ xh, const int* __restrict__ offsets,
    const unsigned long long* __restrict__ records, float* __restrict__ out, int N)
{
    const int lane = threadIdx.x & 63;
    const int row  = blockIdx.x * 4 + (threadIdx.x >> 6);
    if (row >= N) return;

    const int start = offsets[row];
    const int nrec  = offsets[row + 1] - start;

    float accx = 0.f, accy = 0.f;
    for (int chunk = 0; chunk < nrec; chunk += 64) {
        const int m = min(64, nrec - chunk);
        unsigned long long myrec = 0;
        if (lane < m)
            myrec = __builtin_nontemporal_load(&records[start + chunk + lane]);
        const unsigned int mc = (unsigned int)myrec;          // col
        const unsigned int mv = (unsigned int)(myrec >> 32);  // val bits

        if (m == 64) {
            #pragma unroll 4
            for (int j = 0; j < 64; ++j) {
                const unsigned int col = __shfl(mc, j);
                const float v = __uint_as_float(__shfl(mv, j));
                const unsigned int p = *reinterpret_cast<const unsigned int*>(
                    xh + (size_t)col * D_DIM + lane * 2);
                accx += v * __uint_as_float(p << 16);
                accy += v * __uint_as_float(p & 0xFFFF0000u);
            }
        } else {
            for (int j = 0; j < m; ++j) {
                const unsigned int col = __shfl(mc, j);
                const float v = __uint_as_float(__shfl(mv, j));
                const unsigned int p = *reinterpret_cast<const unsigned int*>(
                    xh + (size_t)col * D_DIM + lane * 2);
                accx += v * __uint_as_float(p << 16);
                accy += v * __uint_as_float(p & 0xFFFF0000u);
            }
        }
    }
    *reinterpret_cast<float2*>(out + (size_t)row * D_DIM + lane * 2) =
        make_float2(accx, accy);
}

// ---------- 4b. gather, f32 x (used if workspace can't hold x_bf16) ----------
__global__ __launch_bounds__(256) void gather_f32_kernel(
    const float* __restrict__ x, const int* __restrict__ offsets,
    const unsigned long long* __restrict__ records, float* __restrict__ out, int N)
{
    const int lane = threadIdx.x & 63;
    const int row  = blockIdx.x * 4 + (threadIdx.x >> 6);
    if (row >= N) return;

    const int start = offsets[row];
    const int nrec  = offsets[row + 1] - start;

    float accx = 0.f, accy = 0.f;
    for (int chunk = 0; chunk < nrec; chunk += 64) {
        const int m = min(64, nrec - chunk);
        unsigned long long myrec = 0;
        if (lane < m)
            myrec = __builtin_nontemporal_load(&records[start + chunk + lane]);
        const unsigned int mc = (unsigned int)myrec;
        const unsigned int mv = (unsigned int)(myrec >> 32);

        for (int j = 0; j < m; ++j) {
            const unsigned int col = __shfl(mc, j);
            const float v = __uint_as_float(__shfl(mv, j));
            const float2 xv = *reinterpret_cast<const float2*>(
                x + (size_t)col * D_DIM + lane * 2);
            accx += v * xv.x;
            accy += v * xv.y;
        }
    }
    *reinterpret_cast<float2*>(out + (size_t)row * D_DIM + lane * 2) =
        make_float2(accx, accy);
}

extern "C" void kernel_launch(void* const* d_in, const int* in_sizes, int n_in,
                              void* d_out, int out_size, void* d_ws, size_t ws_size,
                              hipStream_t stream)
{
    const float* x         = (const float*)d_in[0];
    const float* edge_vals = (const float*)d_in[1];
    const float* ws        = (const float*)d_in[2];
    const int*   edge_rows = (const int*)d_in[3];
    const int*   edge_cols = (const int*)d_in[4];
    float*       out       = (float*)d_out;

    const int num_op = in_sizes[2];               // 8
    const int E      = in_sizes[1] / num_op;      // 400000
    const int N      = in_sizes[0] / D_DIM;       // 50000
    const long Etot  = (long)num_op * (long)E;    // 3.2M
    const float inv_num = 1.0f / (float)num_op;

    // workspace layout: offsets | cursors | x_bf16 | records
    const size_t off_offsets = 0;
    const size_t off_cursors = ((size_t)(N + 1) * 4 + 255) & ~(size_t)255;
    const size_t off_xh      = (off_cursors + (size_t)N * 4 + 255) & ~(size_t)255;
    const size_t off_rec_full= (off_xh + (size_t)N * D_DIM * 2 + 255) & ~(size_t)255;
    const size_t need_full   = off_rec_full + (size_t)Etot * 8;
    const size_t off_rec_base= off_xh;            // layout without x_bf16
    const size_t need_base   = off_rec_base + (size_t)Etot * 8;

    if (ws_size < need_base) {
        hipMemsetAsync(d_out, 0, (size_t)out_size * sizeof(float), stream);
        dim3 grid(256, num_op, 1);
        spmm_scatter_kernel<<<grid, 256, 0, stream>>>(
            x, edge_vals, ws, edge_rows, edge_cols, out, E, inv_num);
        return;
    }

    const bool use_bf16 = (ws_size >= need_full);

    int* offsets = (int*)((char*)d_ws + off_offsets);
    int* cursors = (int*)((char*)d_ws + off_cursors);
    unsigned long long* records =
        (unsigned long long*)((char*)d_ws + (use_bf16 ? off_rec_full : off_rec_base));
    unsigned short* xh = (unsigned short*)((char*)d_ws + off_xh);

    hipMemsetAsync(cursors, 0, (size_t)N * 4, stream);

    if (use_bf16) {
        const int n4 = N * D_DIM / 4;
        convert_kernel<<<1024, 256, 0, stream>>>(
            (const float4*)x, (unsigned long long*)xh, n4);
    }

    dim3 egrid(512, num_op, 1);
    histogram_kernel<<<egrid, 256, 0, stream>>>(edge_rows, cursors, E);
    scan_kernel<<<1, SCAN_BLOCK, 0, stream>>>(cursors, offsets, N);
    scatter_build_kernel<<<egrid, 256, 0, stream>>>(
        edge_rows, edge_cols, edge_vals, ws, cursors, records, E, inv_num);

    const int nblocks = (N + 3) / 4;              // 4 rows (waves) per block
    if (use_bf16)
        gather_bf16_kernel<<<nblocks, 256, 0, stream>>>(xh, offsets, records, out, N);
    else
        gather_f32_kernel<<<nblocks, 256, 0, stream>>>(x, offsets, records, out, N);
}

// Round 5
// 386.833 us; speedup vs baseline: 8.8942x; 1.7345x over previous
//
#include <hip/hip_runtime.h>

// Op: out = (1/num_op) * sum_i ws[i] * SpMM(A_i, x).
// Pipeline: x->bf16 | coarse bucket count (row>>5, 1563 bins) | 1563 scan |
//           bucketed scatter (block-local runs, LDS rank) | ballot-filter gather.
// N=50000, D=128, NUM_OP=8, E=400000.

#define D_DIM 128
#define RPB_SHIFT 5
#define RPB 32
#define MAXB 2048
#define CHUNK 16384
#define SCAN_BLOCK 1024

static __device__ __forceinline__ unsigned short f2bf(float f) {
    unsigned int u = __float_as_uint(f);
    u += 0x7FFFu + ((u >> 16) & 1u);          // round-to-nearest-even
    return (unsigned short)(u >> 16);
}

// ---------- fallback (round-0) atomic scatter kernel ----------
__global__ __launch_bounds__(256) void spmm_scatter_kernel(
    const float* __restrict__ x, const float* __restrict__ edge_vals,
    const float* __restrict__ ws, const int* __restrict__ edge_rows,
    const int* __restrict__ edge_cols, float* __restrict__ out,
    int E, float inv_num)
{
    const int  op   = blockIdx.y;
    const long base = (long)op * (long)E;
    const float wscale = ws[op] * inv_num;
    const int lane = threadIdx.x & 63;
    const int wave = blockIdx.x * (blockDim.x >> 6) + (threadIdx.x >> 6);
    const int nwaves = gridDim.x * (blockDim.x >> 6);
    for (int e = wave; e < E; e += nwaves) {
        const int row = edge_rows[base + e];
        const int col = edge_cols[base + e];
        const float v = edge_vals[base + e] * wscale;
        const float2 xv = *reinterpret_cast<const float2*>(x + (long)col * D_DIM + lane * 2);
        float* o = out + (long)row * D_DIM + lane * 2;
        atomicAdd(o, xv.x * v);
        atomicAdd(o + 1, xv.y * v);
    }
}

// ---------- 0. x (f32) -> bf16 ----------
__global__ __launch_bounds__(256) void convert_kernel(
    const float4* __restrict__ x4, unsigned long long* __restrict__ xh, int n4)
{
    const int stride = gridDim.x * blockDim.x;
    for (int i = blockIdx.x * blockDim.x + threadIdx.x; i < n4; i += stride) {
        const float4 v = x4[i];
        const unsigned long long p =
            (unsigned long long)f2bf(v.x)
            | ((unsigned long long)f2bf(v.y) << 16)
            | ((unsigned long long)f2bf(v.z) << 32)
            | ((unsigned long long)f2bf(v.w) << 48);
        xh[i] = p;
    }
}

// ---------- 1. coarse bucket count (LDS-aggregated) ----------
__global__ __launch_bounds__(256) void bucket_count_kernel(
    const int* __restrict__ rows, int* __restrict__ gcount, long n, int B)
{
    __shared__ int h[MAXB];
    for (int i = threadIdx.x; i < B; i += 256) h[i] = 0;
    __syncthreads();
    for (long e = (long)blockIdx.x * 256 + threadIdx.x; e < n;
         e += (long)gridDim.x * 256)
        atomicAdd(&h[__builtin_nontemporal_load(&rows[e]) >> RPB_SHIFT], 1);
    __syncthreads();
    for (int i = threadIdx.x; i < B; i += 256)
        if (h[i]) atomicAdd(&gcount[i], h[i]);
}

// ---------- 2. exclusive scan (single block, proven multi-tile) ----------
__global__ __launch_bounds__(SCAN_BLOCK) void scan_kernel(
    int* __restrict__ cursors, int* __restrict__ offsets, int N)
{
    __shared__ int sdata[SCAN_BLOCK];
    __shared__ int carry_s;
    if (threadIdx.x == 0) carry_s = 0;
    __syncthreads();
    for (int base = 0; base < N; base += SCAN_BLOCK) {
        const int i = base + (int)threadIdx.x;
        const int v = (i < N) ? cursors[i] : 0;
        sdata[threadIdx.x] = v;
        __syncthreads();
        for (int ofs = 1; ofs < SCAN_BLOCK; ofs <<= 1) {
            int t = (threadIdx.x >= (unsigned)ofs) ? sdata[threadIdx.x - ofs] : 0;
            __syncthreads();
            sdata[threadIdx.x] += t;
            __syncthreads();
        }
        const int incl  = sdata[threadIdx.x];
        const int carry = carry_s;
        if (i < N) {
            const int excl = carry + incl - v;
            offsets[i] = excl;
            cursors[i] = excl;
        }
        __syncthreads();
        if (threadIdx.x == SCAN_BLOCK - 1) carry_s = carry + incl;
        __syncthreads();
    }
    if (threadIdx.x == 0) offsets[N] = carry_s;
}

// ---------- 3. bucketed scatter: per-block reservation + LDS rank ----------
__global__ __launch_bounds__(256) void scatter_bucket_kernel(
    const int* __restrict__ edge_rows, const int* __restrict__ edge_cols,
    const float* __restrict__ edge_vals, const float* __restrict__ ws,
    int* __restrict__ gcursor, unsigned long long* __restrict__ records,
    int E, float inv_num, int B)
{
    __shared__ int hist[MAXB];                 // counts, then global-base cursors
    const int  op   = blockIdx.y;
    const long base = (long)op * (long)E;
    const int  e0   = blockIdx.x * CHUNK;
    const int  e1   = min(e0 + CHUNK, E);
    const float wscale = ws[op] * inv_num;

    for (int i = threadIdx.x; i < B; i += 256) hist[i] = 0;
    __syncthreads();
    for (int e = e0 + threadIdx.x; e < e1; e += 256)
        atomicAdd(&hist[edge_rows[base + e] >> RPB_SHIFT], 1);
    __syncthreads();
    for (int i = threadIdx.x; i < B; i += 256) {
        const int c = hist[i];
        hist[i] = c ? atomicAdd(&gcursor[i], c) : 0;   // reserve run, one atomic/bin
    }
    __syncthreads();
    for (int e = e0 + threadIdx.x; e < e1; e += 256) {
        const int   row = edge_rows[base + e];         // L2 re-hit from pass 1
        const int   col = __builtin_nontemporal_load(&edge_cols[base + e]);
        const float v   = __builtin_nontemporal_load(&edge_vals[base + e]) * wscale;
        const int   pos = atomicAdd(&hist[row >> RPB_SHIFT], 1);
        const unsigned long long rec =
            ((unsigned long long)__float_as_uint(v) << 32)
            | ((unsigned int)(row & (RPB - 1)) << 16) | (unsigned int)col;
        records[pos] = rec;                            // plain store -> L2 merge
    }
}

// ---------- 4. ballot-filter gather: one wave per output row ----------
__global__ __launch_bounds__(256) void gather_filter_kernel(
    const unsigned short* __restrict__ xh, const int* __restrict__ boff,
    const unsigned long long* __restrict__ records, float* __restrict__ out, int N)
{
    const int lane = threadIdx.x & 63;
    const int wv   = threadIdx.x >> 6;              // 0..3
    const int bkt  = blockIdx.x;
    const int myrl = blockIdx.y * 4 + wv;           // 0..31
    const int row  = (bkt << RPB_SHIFT) + myrl;
    if (row >= N) return;

    const int start = boff[bkt], end = boff[bkt + 1];

    float accx = 0.f, accy = 0.f;
    for (int c = start; c < end; c += 64) {
        const int idx = c + lane;
        unsigned int lo = 0xFFFF0000u, hi = 0;      // invalid: rl field = 0xFFFF
        if (idx < end) {
            const unsigned long long r = records[idx];
            lo = (unsigned int)r;
            hi = (unsigned int)(r >> 32);
        }
        unsigned long long mask = __ballot((lo >> 16) == (unsigned int)myrl);
        while (mask) {
            const int j = __ffsll(mask) - 1;
            mask &= mask - 1;
            const unsigned int lj = __shfl(lo, j);
            const float v = __uint_as_float(__shfl(hi, j));
            const unsigned int col = lj & 0xFFFFu;
            const unsigned int p = *reinterpret_cast<const unsigned int*>(
                xh + (size_t)col * D_DIM + lane * 2);
            accx += v * __uint_as_float(p << 16);
            accy += v * __uint_as_float(p & 0xFFFF0000u);
        }
    }
    *reinterpret_cast<float2*>(out + (size_t)row * D_DIM + lane * 2) =
        make_float2(accx, accy);
}

extern "C" void kernel_launch(void* const* d_in, const int* in_sizes, int n_in,
                              void* d_out, int out_size, void* d_ws, size_t ws_size,
                              hipStream_t stream)
{
    const float* x         = (const float*)d_in[0];
    const float* edge_vals = (const float*)d_in[1];
    const float* ws        = (const float*)d_in[2];
    const int*   edge_rows = (const int*)d_in[3];
    const int*   edge_cols = (const int*)d_in[4];
    float*       out       = (float*)d_out;

    const int num_op = in_sizes[2];               // 8
    const int E      = in_sizes[1] / num_op;      // 400000
    const int N      = in_sizes[0] / D_DIM;       // 50000
    const long Etot  = (long)num_op * (long)E;    // 3.2M
    const int  B     = (N + RPB - 1) / RPB;       // 1563 buckets
    const float inv_num = 1.0f / (float)num_op;

    // workspace layout: boff | gcursor | x_bf16 | records
    const size_t off_boff    = 0;
    const size_t off_gcur    = ((size_t)(B + 1) * 4 + 255) & ~(size_t)255;
    const size_t off_xh      = (off_gcur + (size_t)B * 4 + 255) & ~(size_t)255;
    const size_t off_records = (off_xh + (size_t)N * D_DIM * 2 + 255) & ~(size_t)255;
    const size_t need        = off_records + (size_t)Etot * 8;

    if (ws_size < need || B > MAXB || N > 65535) {
        hipMemsetAsync(d_out, 0, (size_t)out_size * sizeof(float), stream);
        dim3 grid(256, num_op, 1);
        spmm_scatter_kernel<<<grid, 256, 0, stream>>>(
            x, edge_vals, ws, edge_rows, edge_cols, out, E, inv_num);
        return;
    }

    int* boff    = (int*)((char*)d_ws + off_boff);
    int* gcursor = (int*)((char*)d_ws + off_gcur);
    unsigned short* xh = (unsigned short*)((char*)d_ws + off_xh);
    unsigned long long* records = (unsigned long long*)((char*)d_ws + off_records);

    hipMemsetAsync(gcursor, 0, (size_t)B * 4, stream);

    convert_kernel<<<1024, 256, 0, stream>>>(
        (const float4*)x, (unsigned long long*)xh, N * D_DIM / 4);

    bucket_count_kernel<<<256, 256, 0, stream>>>(edge_rows, gcursor, Etot, B);
    scan_kernel<<<1, SCAN_BLOCK, 0, stream>>>(gcursor, boff, B);

    dim3 sgrid((E + CHUNK - 1) / CHUNK, num_op, 1);   // 25 x 8 blocks
    scatter_bucket_kernel<<<sgrid, 256, 0, stream>>>(
        edge_rows, edge_cols, edge_vals, ws, gcursor, records, E, inv_num, B);

    dim3 ggrid(B, RPB / 4, 1);                        // 1563 x 8, 4 waves/block
    gather_filter_kernel<<<ggrid, 256, 0, stream>>>(xh, boff, records, out, N);
}